// Round 6
// baseline (207.830 us; speedup 1.0000x reference)
//
#include <hip/hip_runtime.h>
#include <hip/hip_bf16.h>
#include <math.h>

// Problem constants
#define Bn 8
#define Sn 4096
#define Dn 512
#define MODES 16
#define ANGF 0.0015339807878856412f  // 2*pi/4096

// ws layout (floats):
#define PART_OFF 0               //  8,388,608  fp32 [B*64][16][512] float2
#define Y_OFF 8388608            //  + 131,072  fp32 [B][16][512] float2
#define WTF_OFF 8519680          //  + 786,432  fp32 [3][512 d][512 o]
#define Z_OFF 9306112            //  + 393,216  fp32 [B][3 t][16][512] float2
#define G_OFF 9699328            //  + 131,072  fp32 [B][16][2][512]
#define V_OFF 9830400            //  +   8,192  fp32 [B][2][512]
#define STATS_OFF 9838592        //  +  65,536  fp32 [B*4096] float2 (mu, rstd)

// ---------------------------------------------------------------------------
// K1a: per-row LayerNorm stats (blocks 0..1023, 32 rows each; wave = 8 rows)
//      + conv_w transpose (blocks 1024..1279): wTf[t][d][o] = cw[o,d,t].
// ---------------------------------------------------------------------------
__global__ __launch_bounds__(256) void k_stats(const float* __restrict__ x,
                                               const float* __restrict__ cw,
                                               float* __restrict__ wTf,
                                               float2* __restrict__ stats) {
  int blk = blockIdx.x;
  int tid = threadIdx.x;

  if (blk >= 1024) {  // transpose path: 256 blocks x 256 thr x 12 elems
    int base0 = (blk - 1024) * 3072;
#pragma unroll
    for (int u = 0; u < 12; ++u) {
      int idx = base0 + (u << 8) + tid;
      int o = idx & 511;
      int d = (idx >> 9) & 511;
      int t = idx >> 18;
      wTf[idx] = cw[o * 1536 + d * 3 + t];
    }
    return;
  }

  int wave = tid >> 6, lane = tid & 63;
  int row0 = blk * 32 + wave * 8;
  for (int j = 0; j < 8; ++j) {
    int row = row0 + j;
    const float4* px = (const float4*)(x + ((size_t)row << 9));
    float4 v0 = px[lane * 2];
    float4 v1 = px[lane * 2 + 1];
    float ps = v0.x + v0.y + v0.z + v0.w + v1.x + v1.y + v1.z + v1.w;
    float pq = v0.x * v0.x + v0.y * v0.y + v0.z * v0.z + v0.w * v0.w +
               v1.x * v1.x + v1.y * v1.y + v1.z * v1.z + v1.w * v1.w;
#pragma unroll
    for (int off = 32; off > 0; off >>= 1) {
      ps += __shfl_down(ps, off);
      pq += __shfl_down(pq, off);
    }
    if (lane == 0) {
      float mu = ps * (1.0f / Dn);
      float var = pq * (1.0f / Dn) - mu * mu;
      stats[row] = make_float2(mu, rsqrtf(var + 1e-5f));
    }
  }
}

// ---------------------------------------------------------------------------
// K1b: radix-4 16-mode DFT projection of LayerNorm output.
// E(s+1024j, k) = E(s,k) * (-i)^{jk}, so rows {s, s+1024, s+2048, s+3072}
// share one twiddle. Chunk c covers base rows c*16..c*16+15 across all 4
// phases (64 rows total). Grid 512 = b(8) x c(64); 256 thr, float2 of d each.
// ---------------------------------------------------------------------------
__global__ __launch_bounds__(256) void k_project(
    const float* __restrict__ x, const float* __restrict__ gamma,
    const float* __restrict__ beta, const float2* __restrict__ stats,
    float* __restrict__ partials) {
  int blk = blockIdx.x;
  int b = blk >> 6;
  int c = blk & 63;
  int tid = threadIdx.x;
  int d0 = tid << 1;
  int s_base = c << 4;  // base rows s_base..s_base+15 (0..1023)

  __shared__ __attribute__((aligned(16))) float2 s_tw[16][MODES];  // 2 KB
  __shared__ float2 s_mv[64];                                      // 512 B
  {
    int r = tid >> 4, k = tid & 15;
    int m = ((s_base + r) * k) & (Sn - 1);
    float sn, cn;
    __sincosf((float)m * ANGF, &sn, &cn);
    s_tw[r][k] = make_float2(cn, sn);
    if (tid < 64) {
      // tid = j*16 + r  ->  row = j*1024 + s_base + r
      s_mv[tid] = stats[(b << 12) + ((tid >> 4) << 10) + s_base + (tid & 15)];
    }
  }
  __syncthreads();

  float2 g = *(const float2*)(gamma + d0);
  float2 be = *(const float2*)(beta + d0);

  float2 accRe[MODES], accIm[MODES];
#pragma unroll
  for (int k = 0; k < MODES; k++) {
    accRe[k] = make_float2(0.f, 0.f);
    accIm[k] = make_float2(0.f, 0.f);
  }

  const float* xb = x + (((size_t)b << 12) << 9) + d0;
  float2 cur[4], nxt[4];
#pragma unroll
  for (int j = 0; j < 4; ++j)
    cur[j] = *(const float2*)(xb + ((size_t)((j << 10) + s_base) << 9));

#pragma unroll 2
  for (int r = 0; r < 16; ++r) {
    if (r < 15) {
#pragma unroll
      for (int j = 0; j < 4; ++j)
        nxt[j] =
            *(const float2*)(xb + ((size_t)((j << 10) + s_base + r + 1) << 9));
    }
    // LayerNorm the 4 phase values
    float2 xn[4];
#pragma unroll
    for (int j = 0; j < 4; ++j) {
      float2 mv = s_mv[(j << 4) + r];
      float ax = mv.y * g.x, ay = mv.y * g.y;
      xn[j] = make_float2((cur[j].x - mv.x) * ax + be.x,
                          (cur[j].y - mv.x) * ay + be.y);
    }
    // radix-4 butterfly (real inputs)
    float2 t02p = make_float2(xn[0].x + xn[2].x, xn[0].y + xn[2].y);
    float2 t02m = make_float2(xn[0].x - xn[2].x, xn[0].y - xn[2].y);
    float2 t13p = make_float2(xn[1].x + xn[3].x, xn[1].y + xn[3].y);
    float2 t13m = make_float2(xn[1].x - xn[3].x, xn[1].y - xn[3].y);
    float2 u0 = make_float2(t02p.x + t13p.x, t02p.y + t13p.y);  // k%4==0
    float2 u1 = make_float2(t02p.x - t13p.x, t02p.y - t13p.y);  // k%4==2

    const float4* twr = (const float4*)&s_tw[r][0];
#pragma unroll
    for (int kk = 0; kk < 8; ++kk) {
      float4 t2 = twr[kk];  // (cos,sin) of modes 2kk and 2kk+1
      const int k0 = 2 * kk, k1 = 2 * kk + 1;
      {  // even mode: real combined input
        float2 u = ((k0 & 3) == 0) ? u0 : u1;
        accRe[k0].x += u.x * t2.x;
        accRe[k0].y += u.y * t2.x;
        accIm[k0].x -= u.x * t2.y;
        accIm[k0].y -= u.y * t2.y;
      }
      if ((k1 & 3) == 1) {  // F = t02m - i*t13m ; acc += (c - i s)*F
        accRe[k1].x += t2.z * t02m.x - t2.w * t13m.x;
        accRe[k1].y += t2.z * t02m.y - t2.w * t13m.y;
        accIm[k1].x -= t2.z * t13m.x + t2.w * t02m.x;
        accIm[k1].y -= t2.z * t13m.y + t2.w * t02m.y;
      } else {  // k%4==3: F = t02m + i*t13m
        accRe[k1].x += t2.z * t02m.x + t2.w * t13m.x;
        accRe[k1].y += t2.z * t02m.y + t2.w * t13m.y;
        accIm[k1].x += t2.z * t13m.x - t2.w * t02m.x;
        accIm[k1].y += t2.z * t13m.y - t2.w * t02m.y;
      }
    }
#pragma unroll
    for (int j = 0; j < 4; ++j) cur[j] = nxt[j];
  }

  size_t base = ((size_t)(b * 64 + c)) * MODES;
  float4* P4 = (float4*)partials;
#pragma unroll
  for (int k = 0; k < MODES; k++)
    P4[(base + k) * 256 + tid] =
        make_float4(accRe[k].x, accIm[k].x, accRe[k].y, accIm[k].y);
}

// ---------------------------------------------------------------------------
// K2: reduce partials over 64 chunks, apply spectral weight, ortho norms.
// ---------------------------------------------------------------------------
__global__ __launch_bounds__(256) void k_reduce_modes(
    const float* __restrict__ partials, const float* __restrict__ wr,
    const float* __restrict__ wi, float* __restrict__ Y) {
  int idx = blockIdx.x * 256 + threadIdx.x;  // 65536
  int d = idx & 511;
  int k = (idx >> 9) & 15;
  int b = idx >> 13;
  const float2* P = (const float2*)partials;
  float re = 0.f, im = 0.f;
#pragma unroll 8
  for (int c = 0; c < 64; c++) {
    float2 p = P[(((size_t)(b * 64 + c)) * MODES + k) * Dn + d];
    re += p.x;
    im += p.y;
  }
  float wrv = wr[d * MODES + k];
  float wiv = wi[d * MODES + k];
  float yre = re * wrv - im * wiv;
  float yim = re * wiv + im * wrv;
  float scale = (k == 0) ? (1.0f / 4096.0f) : (2.0f / 4096.0f);
  ((float2*)Y)[((size_t)b * MODES + k) * Dn + d] =
      make_float2(yre * scale, yim * scale);
}

// ---------------------------------------------------------------------------
// KZ: Z[b,t][k][o] = sum_d Yhat[b,k,d] * w[o,d,t]  (FULLY summed over d).
// Grid 768 = b(8) x t(3) x och(32); 256 thr = 16 k x 16 o (one pair each).
// LDS Y-tile [16][129] (padded). Whole wave reads one 64B wTf line per step.
// ---------------------------------------------------------------------------
__global__ __launch_bounds__(256) void k_build_z(
    const float* __restrict__ Y, const float* __restrict__ wTf,
    float* __restrict__ Z) {
  int blk = blockIdx.x;
  int b = blk / 96;
  int rem = blk % 96;
  int t = rem >> 5;
  int och = rem & 31;
  int tid = threadIdx.x;
  int k = tid >> 4, oi = tid & 15;
  int o = (och << 4) + oi;

  __shared__ float2 Ys[MODES][129];  // ~16.1 KB
  const float2* Y2 = (const float2*)Y;

  float zc = 0.f, zs = 0.f;
  for (int dch = 0; dch < 4; ++dch) {
    int d0 = dch << 7;
#pragma unroll
    for (int i = 0; i < 8; i++) {
      int e = tid + (i << 8);  // 2048
      int kk = e >> 7, dd = e & 127;
      Ys[kk][dd] = Y2[(((size_t)(b * MODES + kk)) << 9) + d0 + dd];
    }
    __syncthreads();

    const float* wp = wTf + (((size_t)(t * Dn + d0)) << 9) + o;
#pragma unroll 8
    for (int dd = 0; dd < 128; ++dd) {
      float wv = wp[(size_t)dd << 9];
      float2 y = Ys[k][dd];
      zc += y.x * wv;
      zs += y.y * wv;
    }
    __syncthreads();
  }

  ((float2*)Z)[(((size_t)((b * 3 + t) * MODES + k)) << 9) + o] =
      make_float2(zc, zs);
}

// ---------------------------------------------------------------------------
// KG: G[b][k][comp][o] = Yhat + e^{-i phi} Z0 + Z1 + e^{+i phi} Z2
// (phi = 2pi k/S), conv_b folded into Gc[0] (k=0 twiddle == 1 for all s,
// all phases). Boundary vectors V0 = sum_k Re(e^{-i phi} Z0) (s=0 wrap),
// V1 = sum_k Re(Z2) (s=S-1). Grid 288 x 256.
// ---------------------------------------------------------------------------
__global__ __launch_bounds__(256) void k_build_g(
    const float* __restrict__ Y, const float* __restrict__ Z,
    const float* __restrict__ conv_b, float* __restrict__ G,
    float* __restrict__ V) {
  int idx = blockIdx.x * 256 + threadIdx.x;
  const float2* Y2 = (const float2*)Y;
  const float2* Z2 = (const float2*)Z;
  if (idx < 65536) {
    int o = idx & 511;
    int k = (idx >> 9) & 15;
    int b = idx >> 13;
    float2 z0 = Z2[(((size_t)((b * 3 + 0) * MODES + k)) << 9) + o];
    float2 z1 = Z2[(((size_t)((b * 3 + 1) * MODES + k)) << 9) + o];
    float2 z2 = Z2[(((size_t)((b * 3 + 2) * MODES + k)) << 9) + o];
    float2 y = Y2[(((size_t)(b * MODES + k)) << 9) + o];
    float sf, cf;
    __sincosf((float)k * ANGF, &sf, &cf);
    float gc = y.x + (cf * z0.x + sf * z0.y) + z1.x + (cf * z2.x - sf * z2.y);
    float gs = y.y + (cf * z0.y - sf * z0.x) + z1.y + (cf * z2.y + sf * z2.x);
    if (k == 0) gc += conv_b[o];
    G[(((size_t)(b * MODES + k) * 2 + 0)) << 9 | o] = gc;
    G[(((size_t)(b * MODES + k) * 2 + 1)) << 9 | o] = gs;
  } else if (idx < 65536 + 8192) {
    int j = idx - 65536;
    int o = j & 511;
    int comp = (j >> 9) & 1;
    int b = j >> 10;
    float v = 0.f;
#pragma unroll
    for (int k = 0; k < MODES; k++) {
      float2 z =
          Z2[(((size_t)((b * 3 + (comp ? 2 : 0)) * MODES + k)) << 9) + o];
      if (comp == 0) {
        float sf, cf;
        __sincosf((float)k * ANGF, &sf, &cf);
        v += cf * z.x + sf * z.y;
      } else {
        v += z.x;
      }
    }
    V[((size_t)(b * 2 + comp) << 9) + o] = v;
  }
}

// ---------------------------------------------------------------------------
// K5: out[b,s,o] = x + sum_k Re(G_k * e^{i*2pi*s*k/S}) (conv_b folded into
// Gc[0]), minus V0 at s=0 / V1 at s=S-1. Radix-4 over phases j*1024 via
// i^{jk}. Light prologue: 32 float2 G loads per thread (G is L2-resident).
// Grid 1024 = b(8) x rt(128); 8 base rows per block; float2 of o per thread.
// ---------------------------------------------------------------------------
__global__ __launch_bounds__(256) void k_apply(
    const float* __restrict__ x, const float* __restrict__ G,
    const float* __restrict__ V, float* __restrict__ out) {
  int b = blockIdx.x >> 7;
  int rt = blockIdx.x & 127;
  int r0 = rt << 3;  // base rows r0..r0+7 (0..1023)
  int tid = threadIdx.x;
  int o0 = tid << 1;

  __shared__ __attribute__((aligned(16))) float2 s_tw[8][MODES];  // 1 KB
  if (tid < 128) {
    int rr = tid >> 4, k = tid & 15;
    int m = ((r0 + rr) * k) & (Sn - 1);
    float sn, cn;
    __sincosf((float)m * ANGF, &sn, &cn);
    s_tw[rr][k] = make_float2(cn, sn);
  }

  float2 Gc[MODES], Gs[MODES];
  const float2* Gp = (const float2*)(G + ((size_t)b * MODES * 2 * Dn));
#pragma unroll
  for (int k = 0; k < MODES; k++) {
    Gc[k] = Gp[(k * 2 + 0) * 256 + tid];
    Gs[k] = Gp[(k * 2 + 1) * 256 + tid];
  }
  float2 v0 = *(const float2*)&V[((size_t)(b * 2 + 0) << 9) + o0];
  float2 v1 = *(const float2*)&V[((size_t)(b * 2 + 1) << 9) + o0];
  __syncthreads();

  const float* xb = x + (((size_t)b << 12) << 9) + o0;
  float* ob = out + (((size_t)b << 12) << 9) + o0;

  float2 cur[4], nxt[4];
#pragma unroll
  for (int j = 0; j < 4; ++j)
    cur[j] = *(const float2*)(xb + ((size_t)((j << 10) + r0) << 9));

#pragma unroll 2
  for (int rr = 0; rr < 8; ++rr) {
    if (rr < 7) {
#pragma unroll
      for (int j = 0; j < 4; ++j)
        nxt[j] = *(const float2*)(xb + ((size_t)((j << 10) + r0 + rr + 1) << 9));
    }
    float2 a0 = make_float2(0.f, 0.f), a1 = a0, a2 = a0, a3 = a0;
    const float4* twr = (const float4*)&s_tw[rr][0];
#pragma unroll
    for (int kk = 0; kk < 8; ++kk) {
      float4 t2 = twr[kk];
#define APPLY_K(kidx, cc, ss)                                          \
  {                                                                    \
    float2 Pre = make_float2(cc * Gc[kidx].x - ss * Gs[kidx].x,        \
                             cc * Gc[kidx].y - ss * Gs[kidx].y);       \
    float2 Pim = make_float2(cc * Gs[kidx].x + ss * Gc[kidx].x,        \
                             cc * Gs[kidx].y + ss * Gc[kidx].y);       \
    a0.x += Pre.x; a0.y += Pre.y;                                      \
    if (((kidx) & 3) == 0) {                                           \
      a1.x += Pre.x; a1.y += Pre.y;                                    \
      a2.x += Pre.x; a2.y += Pre.y;                                    \
      a3.x += Pre.x; a3.y += Pre.y;                                    \
    } else if (((kidx) & 3) == 1) {                                    \
      a1.x -= Pim.x; a1.y -= Pim.y;                                    \
      a2.x -= Pre.x; a2.y -= Pre.y;                                    \
      a3.x += Pim.x; a3.y += Pim.y;                                    \
    } else if (((kidx) & 3) == 2) {                                    \
      a1.x -= Pre.x; a1.y -= Pre.y;                                    \
      a2.x += Pre.x; a2.y += Pre.y;                                    \
      a3.x -= Pre.x; a3.y -= Pre.y;                                    \
    } else {                                                           \
      a1.x += Pim.x; a1.y += Pim.y;                                    \
      a2.x -= Pre.x; a2.y -= Pre.y;                                    \
      a3.x -= Pim.x; a3.y -= Pim.y;                                    \
    }                                                                  \
  }
      APPLY_K(2 * kk, t2.x, t2.y);
      APPLY_K(2 * kk + 1, t2.z, t2.w);
#undef APPLY_K
    }
    int s_r = r0 + rr;
#pragma unroll
    for (int j = 0; j < 4; ++j) {
      float2 aj = (j == 0) ? a0 : (j == 1) ? a1 : (j == 2) ? a2 : a3;
      int s = s_r + (j << 10);
      float2 o2 = make_float2(cur[j].x + aj.x, cur[j].y + aj.y);
      if (s == 0) { o2.x -= v0.x; o2.y -= v0.y; }
      if (s == Sn - 1) { o2.x -= v1.x; o2.y -= v1.y; }
      *(float2*)(ob + ((size_t)s << 9)) = o2;
    }
#pragma unroll
    for (int j = 0; j < 4; ++j) cur[j] = nxt[j];
  }
}

// ---------------------------------------------------------------------------
extern "C" void kernel_launch(void* const* d_in, const int* in_sizes, int n_in,
                              void* d_out, int out_size, void* d_ws,
                              size_t ws_size, hipStream_t stream) {
  const float* x = (const float*)d_in[0];
  const float* gamma = (const float*)d_in[1];
  const float* beta = (const float*)d_in[2];
  const float* wr = (const float*)d_in[3];
  const float* wi = (const float*)d_in[4];
  const float* conv_w = (const float*)d_in[5];
  const float* conv_b = (const float*)d_in[6];
  float* out = (float*)d_out;

  float* ws = (float*)d_ws;
  float* partials = ws + PART_OFF;
  float* Y = ws + Y_OFF;
  float* wTf = ws + WTF_OFF;
  float* Z = ws + Z_OFF;
  float* G = ws + G_OFF;
  float* V = ws + V_OFF;
  float2* stats = (float2*)(ws + STATS_OFF);

  hipLaunchKernelGGL(k_stats, dim3(1280), dim3(256), 0, stream, x, conv_w,
                     wTf, stats);
  hipLaunchKernelGGL(k_project, dim3(512), dim3(256), 0, stream, x, gamma,
                     beta, stats, partials);
  hipLaunchKernelGGL(k_reduce_modes, dim3(256), dim3(256), 0, stream, partials,
                     wr, wi, Y);
  hipLaunchKernelGGL(k_build_z, dim3(768), dim3(256), 0, stream, Y, wTf, Z);
  hipLaunchKernelGGL(k_build_g, dim3(288), dim3(256), 0, stream, Y, Z, conv_b,
                     G, V);
  hipLaunchKernelGGL(k_apply, dim3(1024), dim3(256), 0, stream, x, G, V, out);
}

// Round 7
// 190.473 us; speedup vs baseline: 1.0911x; 1.0911x over previous
//
#include <hip/hip_runtime.h>
#include <hip/hip_bf16.h>
#include <math.h>

// Problem constants
#define Bn 8
#define Sn 4096
#define Dn 512
#define MODES 16
#define ANGF 0.0015339807878856412f  // 2*pi/4096

// ws layout (floats):
#define PART_OFF 0               //  8,388,608  fp32 [B*64][16][512] float2
#define Y_OFF 8388608            //  + 131,072  fp32 [B][16][512] float2
#define WTF_OFF 8519680          //  + 786,432  fp32 [3][512 d][512 o]
#define ZP_OFF 9306112           //  +1,572,864 fp32 [4 dch][B*3][16][512] float2
#define G_OFF 10878976           //  + 131,072  fp32 [B][16][2][512]
#define V_OFF 11010048           //  +   8,192  fp32 [B][2][512]
#define STATS_OFF 11018240       //  +  65,536  fp32 [B*4096] float2 (mu, rstd)

// ---------------------------------------------------------------------------
// K0: transpose conv_w (O,I,3) -> wTf[t][d][o] (coalesced o-writes)
// ---------------------------------------------------------------------------
__global__ __launch_bounds__(256) void k_transpose_w(
    const float* __restrict__ cw, float* __restrict__ wTf) {
  int idx = blockIdx.x * 256 + threadIdx.x;  // 786432
  int o = idx & 511;
  int d = (idx >> 9) & 511;
  int t = idx >> 18;
  wTf[idx] = cw[o * 1536 + d * 3 + t];
}

// ---------------------------------------------------------------------------
// K1a: per-row LayerNorm stats. Grid 1024 x 256 thr; wave handles 8 rows.
// ---------------------------------------------------------------------------
__global__ __launch_bounds__(256) void k_stats(const float* __restrict__ x,
                                               float2* __restrict__ stats) {
  int wave = threadIdx.x >> 6, lane = threadIdx.x & 63;
  int row0 = blockIdx.x * 32 + wave * 8;
  for (int j = 0; j < 8; ++j) {
    int row = row0 + j;
    const float4* px = (const float4*)(x + ((size_t)row << 9));
    float4 v0 = px[lane * 2];
    float4 v1 = px[lane * 2 + 1];
    float ps = v0.x + v0.y + v0.z + v0.w + v1.x + v1.y + v1.z + v1.w;
    float pq = v0.x * v0.x + v0.y * v0.y + v0.z * v0.z + v0.w * v0.w +
               v1.x * v1.x + v1.y * v1.y + v1.z * v1.z + v1.w * v1.w;
#pragma unroll
    for (int off = 32; off > 0; off >>= 1) {
      ps += __shfl_down(ps, off);
      pq += __shfl_down(pq, off);
    }
    if (lane == 0) {
      float mu = ps * (1.0f / Dn);
      float var = pq * (1.0f / Dn) - mu * mu;
      stats[row] = make_float2(mu, rsqrtf(var + 1e-5f));
    }
  }
}

// ---------------------------------------------------------------------------
// K1b: radix-4 16-mode DFT projection of LayerNorm output.
// E(s+1024j, k) = E(s,k) * (-i)^{jk}, so rows {s, s+1024, s+2048, s+3072}
// share one twiddle. Chunk c covers base rows c*16..c*16+15 across all 4
// phases (64 rows total). Grid 512 = b(8) x c(64); 256 thr, float2 of d each.
// ---------------------------------------------------------------------------
__global__ __launch_bounds__(256) void k_project(
    const float* __restrict__ x, const float* __restrict__ gamma,
    const float* __restrict__ beta, const float2* __restrict__ stats,
    float* __restrict__ partials) {
  int blk = blockIdx.x;
  int b = blk >> 6;
  int c = blk & 63;
  int tid = threadIdx.x;
  int d0 = tid << 1;
  int s_base = c << 4;  // base rows s_base..s_base+15 (0..1023)

  __shared__ __attribute__((aligned(16))) float2 s_tw[16][MODES];  // 2 KB
  __shared__ float2 s_mv[64];                                      // 512 B
  {
    int r = tid >> 4, k = tid & 15;
    int m = ((s_base + r) * k) & (Sn - 1);
    float sn, cn;
    __sincosf((float)m * ANGF, &sn, &cn);
    s_tw[r][k] = make_float2(cn, sn);
    if (tid < 64) {
      // tid = j*16 + r  ->  row = j*1024 + s_base + r
      s_mv[tid] = stats[(b << 12) + ((tid >> 4) << 10) + s_base + (tid & 15)];
    }
  }
  __syncthreads();

  float2 g = *(const float2*)(gamma + d0);
  float2 be = *(const float2*)(beta + d0);

  float2 accRe[MODES], accIm[MODES];
#pragma unroll
  for (int k = 0; k < MODES; k++) {
    accRe[k] = make_float2(0.f, 0.f);
    accIm[k] = make_float2(0.f, 0.f);
  }

  const float* xb = x + (((size_t)b << 12) << 9) + d0;
  float2 cur[4], nxt[4];
#pragma unroll
  for (int j = 0; j < 4; ++j)
    cur[j] = *(const float2*)(xb + ((size_t)((j << 10) + s_base) << 9));

#pragma unroll 2
  for (int r = 0; r < 16; ++r) {
    if (r < 15) {
#pragma unroll
      for (int j = 0; j < 4; ++j)
        nxt[j] =
            *(const float2*)(xb + ((size_t)((j << 10) + s_base + r + 1) << 9));
    }
    // LayerNorm the 4 phase values
    float2 xn[4];
#pragma unroll
    for (int j = 0; j < 4; ++j) {
      float2 mv = s_mv[(j << 4) + r];
      float ax = mv.y * g.x, ay = mv.y * g.y;
      xn[j] = make_float2((cur[j].x - mv.x) * ax + be.x,
                          (cur[j].y - mv.x) * ay + be.y);
    }
    // radix-4 butterfly (real inputs)
    float2 t02p = make_float2(xn[0].x + xn[2].x, xn[0].y + xn[2].y);
    float2 t02m = make_float2(xn[0].x - xn[2].x, xn[0].y - xn[2].y);
    float2 t13p = make_float2(xn[1].x + xn[3].x, xn[1].y + xn[3].y);
    float2 t13m = make_float2(xn[1].x - xn[3].x, xn[1].y - xn[3].y);
    float2 u0 = make_float2(t02p.x + t13p.x, t02p.y + t13p.y);  // k%4==0
    float2 u1 = make_float2(t02p.x - t13p.x, t02p.y - t13p.y);  // k%4==2

    const float4* twr = (const float4*)&s_tw[r][0];
#pragma unroll
    for (int kk = 0; kk < 8; ++kk) {
      float4 t2 = twr[kk];  // (cos,sin) of modes 2kk and 2kk+1
      const int k0 = 2 * kk, k1 = 2 * kk + 1;
      {  // even mode: real combined input
        float2 u = ((k0 & 3) == 0) ? u0 : u1;
        accRe[k0].x += u.x * t2.x;
        accRe[k0].y += u.y * t2.x;
        accIm[k0].x -= u.x * t2.y;
        accIm[k0].y -= u.y * t2.y;
      }
      if ((k1 & 3) == 1) {  // F = t02m - i*t13m ; acc += (c - i s)*F
        accRe[k1].x += t2.z * t02m.x - t2.w * t13m.x;
        accRe[k1].y += t2.z * t02m.y - t2.w * t13m.y;
        accIm[k1].x -= t2.z * t13m.x + t2.w * t02m.x;
        accIm[k1].y -= t2.z * t13m.y + t2.w * t02m.y;
      } else {  // k%4==3: F = t02m + i*t13m
        accRe[k1].x += t2.z * t02m.x + t2.w * t13m.x;
        accRe[k1].y += t2.z * t02m.y + t2.w * t13m.y;
        accIm[k1].x += t2.z * t13m.x - t2.w * t02m.x;
        accIm[k1].y += t2.z * t13m.y - t2.w * t02m.y;
      }
    }
#pragma unroll
    for (int j = 0; j < 4; ++j) cur[j] = nxt[j];
  }

  size_t base = ((size_t)(b * 64 + c)) * MODES;
  float4* P4 = (float4*)partials;
#pragma unroll
  for (int k = 0; k < MODES; k++)
    P4[(base + k) * 256 + tid] =
        make_float4(accRe[k].x, accIm[k].x, accRe[k].y, accIm[k].y);
}

// ---------------------------------------------------------------------------
// K2: reduce partials over 64 chunks, apply spectral weight, ortho norms.
// ---------------------------------------------------------------------------
__global__ __launch_bounds__(256) void k_reduce_modes(
    const float* __restrict__ partials, const float* __restrict__ wr,
    const float* __restrict__ wi, float* __restrict__ Y) {
  int idx = blockIdx.x * 256 + threadIdx.x;  // 65536
  int d = idx & 511;
  int k = (idx >> 9) & 15;
  int b = idx >> 13;
  const float2* P = (const float2*)partials;
  float re = 0.f, im = 0.f;
#pragma unroll 8
  for (int c = 0; c < 64; c++) {
    float2 p = P[(((size_t)(b * 64 + c)) * MODES + k) * Dn + d];
    re += p.x;
    im += p.y;
  }
  float wrv = wr[d * MODES + k];
  float wiv = wi[d * MODES + k];
  float yre = re * wrv - im * wiv;
  float yim = re * wiv + im * wrv;
  float scale = (k == 0) ? (1.0f / 4096.0f) : (2.0f / 4096.0f);
  ((float2*)Y)[((size_t)b * MODES + k) * Dn + d] =
      make_float2(yre * scale, yim * scale);
}

// ---------------------------------------------------------------------------
// KZ: Zp[dch][b,t][k][o] = sum_{d in chunk} Yhat[b,k,d] * w[o,d,t].
// Grid 768 = b(8) x t(3) x och(8) x dch(4). Wave = 4 modes, lanes = 64 o
// (64-lane-coalesced wTf walk, 256B/wave-step). Depth-1 prefetch on wv.
// ---------------------------------------------------------------------------
__global__ __launch_bounds__(256) void k_build_z(
    const float* __restrict__ Y, const float* __restrict__ wTf,
    float* __restrict__ Zp) {
  int blk = blockIdx.x;
  int b = blk / 96;
  int rem = blk % 96;
  int t = rem >> 5;
  int r2 = rem & 31;
  int och = r2 >> 2;
  int dch = r2 & 3;
  int tid = threadIdx.x;
  int oi = tid & 63, kq = tid >> 6;
  int o = och * 64 + oi;
  int d0 = dch * 128;

  __shared__ float2 Ys[MODES][128];  // 16 KB
  const float2* Y2 = (const float2*)Y;
#pragma unroll
  for (int i = 0; i < 8; i++) {
    int e = tid + i * 256;  // 2048
    int k = e >> 7, dd = e & 127;
    Ys[k][dd] = Y2[(((size_t)(b * MODES + k)) << 9) + d0 + dd];
  }
  __syncthreads();

  float zc[4] = {0.f, 0.f, 0.f, 0.f}, zs[4] = {0.f, 0.f, 0.f, 0.f};
  const float* wp = wTf + (((size_t)(t * Dn + d0)) << 9) + o;
  float wv_n = wp[0];
  for (int dd = 0; dd < 128; ++dd) {
    float wv = wv_n;
    if (dd < 127) wv_n = wp[(size_t)(dd + 1) << 9];
#pragma unroll
    for (int m = 0; m < 4; m++) {
      float2 y = Ys[kq * 4 + m][dd];
      zc[m] += y.x * wv;
      zs[m] += y.y * wv;
    }
  }
  float2* Z2 = (float2*)Zp;
#pragma unroll
  for (int m = 0; m < 4; m++) {
    int k = kq * 4 + m;
    Z2[(((size_t)(dch * 24 + b * 3 + t) * MODES + k)) << 9 | o] =
        make_float2(zc[m], zs[m]);
  }
}

// ---------------------------------------------------------------------------
// KG: G[b][k][o] = Yhat + e^{-i phi} Z0 + Z1 + e^{+i phi} Z2 (phi = 2pi k/S),
// summing the 4 d-chunk partials of Z; conv_b folded into Gc[0] (k=0 twiddle
// == 1 for every s and every phase). Boundary vectors V0 = sum_k
// Re(e^{-i phi} Z0) (s=0 wrap), V1 = sum_k Re(Z2) (s=S-1). Grid 288 x 256.
// ---------------------------------------------------------------------------
__global__ __launch_bounds__(256) void k_build_g(
    const float* __restrict__ Y, const float* __restrict__ Zp,
    const float* __restrict__ conv_b, float* __restrict__ G,
    float* __restrict__ V) {
  int idx = blockIdx.x * 256 + threadIdx.x;
  const float2* Y2 = (const float2*)Y;
  const float2* Z2 = (const float2*)Zp;
  if (idx < 65536) {
    int o = idx & 511;
    int k = (idx >> 9) & 15;
    int b = idx >> 13;
    float2 z0 = make_float2(0.f, 0.f), z1 = z0, z2 = z0;
#pragma unroll
    for (int dch = 0; dch < 4; dch++) {
      float2 a0 = Z2[(((size_t)(dch * 24 + b * 3 + 0) * MODES + k)) << 9 | o];
      float2 a1 = Z2[(((size_t)(dch * 24 + b * 3 + 1) * MODES + k)) << 9 | o];
      float2 a2 = Z2[(((size_t)(dch * 24 + b * 3 + 2) * MODES + k)) << 9 | o];
      z0.x += a0.x; z0.y += a0.y;
      z1.x += a1.x; z1.y += a1.y;
      z2.x += a2.x; z2.y += a2.y;
    }
    float2 y = Y2[(((size_t)(b * MODES + k)) << 9) + o];
    float sf, cf;
    __sincosf((float)k * ANGF, &sf, &cf);
    float gc = y.x + (cf * z0.x + sf * z0.y) + z1.x + (cf * z2.x - sf * z2.y);
    float gs = y.y + (cf * z0.y - sf * z0.x) + z1.y + (cf * z2.y + sf * z2.x);
    if (k == 0) gc += conv_b[o];
    G[(((size_t)(b * MODES + k) * 2 + 0)) << 9 | o] = gc;
    G[(((size_t)(b * MODES + k) * 2 + 1)) << 9 | o] = gs;
  } else if (idx < 65536 + 8192) {
    int j = idx - 65536;
    int o = j & 511;
    int comp = (j >> 9) & 1;
    int b = j >> 10;
    float v = 0.f;
#pragma unroll
    for (int k = 0; k < MODES; k++) {
      float2 z = make_float2(0.f, 0.f);
#pragma unroll
      for (int dch = 0; dch < 4; dch++) {
        float2 a = Z2[(((size_t)(dch * 24 + b * 3 + (comp ? 2 : 0)) * MODES +
                        k)) << 9 | o];
        z.x += a.x; z.y += a.y;
      }
      if (comp == 0) {
        float sf, cf;
        __sincosf((float)k * ANGF, &sf, &cf);
        v += cf * z.x + sf * z.y;
      } else {
        v += z.x;
      }
    }
    V[((size_t)(b * 2 + comp) << 9) + o] = v;
  }
}

// ---------------------------------------------------------------------------
// K5: out[b,s,o] = x + sum_k Re(G_k * e^{i*2pi*s*k/S}) (conv_b folded into
// Gc[0]), minus V0 at s=0 / V1 at s=S-1. Radix-4 over phases j*1024 via
// i^{jk}. Grid 1024 = b(8) x rt(128); 8 base rows per block; float2 of o
// per thread.
// ---------------------------------------------------------------------------
__global__ __launch_bounds__(256) void k_apply(
    const float* __restrict__ x, const float* __restrict__ G,
    const float* __restrict__ V, float* __restrict__ out) {
  int b = blockIdx.x >> 7;
  int rt = blockIdx.x & 127;
  int r0 = rt << 3;  // base rows r0..r0+7 (0..1023)
  int tid = threadIdx.x;
  int o0 = tid << 1;

  __shared__ __attribute__((aligned(16))) float2 s_tw[8][MODES];  // 1 KB
  if (tid < 128) {
    int rr = tid >> 4, k = tid & 15;
    int m = ((r0 + rr) * k) & (Sn - 1);
    float sn, cn;
    __sincosf((float)m * ANGF, &sn, &cn);
    s_tw[rr][k] = make_float2(cn, sn);
  }

  float2 Gc[MODES], Gs[MODES];
  const float2* Gp = (const float2*)(G + ((size_t)b * MODES * 2 * Dn));
#pragma unroll
  for (int k = 0; k < MODES; k++) {
    Gc[k] = Gp[(k * 2 + 0) * 256 + tid];
    Gs[k] = Gp[(k * 2 + 1) * 256 + tid];
  }
  float2 v0 = *(const float2*)&V[((size_t)(b * 2 + 0) << 9) + o0];
  float2 v1 = *(const float2*)&V[((size_t)(b * 2 + 1) << 9) + o0];
  __syncthreads();

  const float* xb = x + (((size_t)b << 12) << 9) + o0;
  float* ob = out + (((size_t)b << 12) << 9) + o0;

  float2 cur[4], nxt[4];
#pragma unroll
  for (int j = 0; j < 4; ++j)
    cur[j] = *(const float2*)(xb + ((size_t)((j << 10) + r0) << 9));

#pragma unroll 2
  for (int rr = 0; rr < 8; ++rr) {
    if (rr < 7) {
#pragma unroll
      for (int j = 0; j < 4; ++j)
        nxt[j] = *(const float2*)(xb + ((size_t)((j << 10) + r0 + rr + 1) << 9));
    }
    float2 a0 = make_float2(0.f, 0.f), a1 = a0, a2 = a0, a3 = a0;
    const float4* twr = (const float4*)&s_tw[rr][0];
#pragma unroll
    for (int kk = 0; kk < 8; ++kk) {
      float4 t2 = twr[kk];
#define APPLY_K(kidx, cc, ss)                                          \
  {                                                                    \
    float2 Pre = make_float2(cc * Gc[kidx].x - ss * Gs[kidx].x,        \
                             cc * Gc[kidx].y - ss * Gs[kidx].y);       \
    float2 Pim = make_float2(cc * Gs[kidx].x + ss * Gc[kidx].x,        \
                             cc * Gs[kidx].y + ss * Gc[kidx].y);       \
    a0.x += Pre.x; a0.y += Pre.y;                                      \
    if (((kidx) & 3) == 0) {                                           \
      a1.x += Pre.x; a1.y += Pre.y;                                    \
      a2.x += Pre.x; a2.y += Pre.y;                                    \
      a3.x += Pre.x; a3.y += Pre.y;                                    \
    } else if (((kidx) & 3) == 1) {                                    \
      a1.x -= Pim.x; a1.y -= Pim.y;                                    \
      a2.x -= Pre.x; a2.y -= Pre.y;                                    \
      a3.x += Pim.x; a3.y += Pim.y;                                    \
    } else if (((kidx) & 3) == 2) {                                    \
      a1.x -= Pre.x; a1.y -= Pre.y;                                    \
      a2.x += Pre.x; a2.y += Pre.y;                                    \
      a3.x -= Pre.x; a3.y -= Pre.y;                                    \
    } else {                                                           \
      a1.x += Pim.x; a1.y += Pim.y;                                    \
      a2.x -= Pre.x; a2.y -= Pre.y;                                    \
      a3.x -= Pim.x; a3.y -= Pim.y;                                    \
    }                                                                  \
  }
      APPLY_K(2 * kk, t2.x, t2.y);
      APPLY_K(2 * kk + 1, t2.z, t2.w);
#undef APPLY_K
    }
    int s_r = r0 + rr;
#pragma unroll
    for (int j = 0; j < 4; ++j) {
      float2 aj = (j == 0) ? a0 : (j == 1) ? a1 : (j == 2) ? a2 : a3;
      int s = s_r + (j << 10);
      float2 o2 = make_float2(cur[j].x + aj.x, cur[j].y + aj.y);
      if (s == 0) { o2.x -= v0.x; o2.y -= v0.y; }
      if (s == Sn - 1) { o2.x -= v1.x; o2.y -= v1.y; }
      *(float2*)(ob + ((size_t)s << 9)) = o2;
    }
#pragma unroll
    for (int j = 0; j < 4; ++j) cur[j] = nxt[j];
  }
}

// ---------------------------------------------------------------------------
extern "C" void kernel_launch(void* const* d_in, const int* in_sizes, int n_in,
                              void* d_out, int out_size, void* d_ws,
                              size_t ws_size, hipStream_t stream) {
  const float* x = (const float*)d_in[0];
  const float* gamma = (const float*)d_in[1];
  const float* beta = (const float*)d_in[2];
  const float* wr = (const float*)d_in[3];
  const float* wi = (const float*)d_in[4];
  const float* conv_w = (const float*)d_in[5];
  const float* conv_b = (const float*)d_in[6];
  float* out = (float*)d_out;

  float* ws = (float*)d_ws;
  float* partials = ws + PART_OFF;
  float* Y = ws + Y_OFF;
  float* wTf = ws + WTF_OFF;
  float* Zp = ws + ZP_OFF;
  float* G = ws + G_OFF;
  float* V = ws + V_OFF;
  float2* stats = (float2*)(ws + STATS_OFF);

  hipLaunchKernelGGL(k_transpose_w, dim3(3072), dim3(256), 0, stream, conv_w,
                     wTf);
  hipLaunchKernelGGL(k_stats, dim3(1024), dim3(256), 0, stream, x, stats);
  hipLaunchKernelGGL(k_project, dim3(512), dim3(256), 0, stream, x, gamma,
                     beta, stats, partials);
  hipLaunchKernelGGL(k_reduce_modes, dim3(256), dim3(256), 0, stream, partials,
                     wr, wi, Y);
  hipLaunchKernelGGL(k_build_z, dim3(768), dim3(256), 0, stream, Y, wTf, Zp);
  hipLaunchKernelGGL(k_build_g, dim3(288), dim3(256), 0, stream, Y, Zp, conv_b,
                     G, V);
  hipLaunchKernelGGL(k_apply, dim3(1024), dim3(256), 0, stream, x, G, V, out);
}

// Round 8
// 189.172 us; speedup vs baseline: 1.0986x; 1.0069x over previous
//
#include <hip/hip_runtime.h>
#include <hip/hip_bf16.h>
#include <math.h>

// Problem constants
#define Bn 8
#define Sn 4096
#define Dn 512
#define MODES 16
#define ANGF 0.0015339807878856412f  // 2*pi/4096

// ws layout (floats):
#define PART_OFF 0               //  8,388,608  fp32 [B*64][16][512] float2
#define Y_OFF 8388608            //  + 131,072  fp32 [B][16][512] float2
#define WTF_OFF 8519680          //  + 786,432  fp32 [3][512 d][512 o]
#define ZP_OFF 9306112           //  +1,572,864 fp32 [4 dch][B*3][16][512] float2
#define G_OFF 10878976           //  + 131,072  fp32 [B][16][2][512]
#define V_OFF 11010048           //  +   8,192  fp32 [B][2][512]
#define STATS_OFF 11018240       //  +  65,536  fp32 [B*4096] float2 (mu, rstd)

// ---------------------------------------------------------------------------
// K0: transpose conv_w (O,I,3) -> wTf[t][d][o] (coalesced o-writes)
// ---------------------------------------------------------------------------
__global__ __launch_bounds__(256) void k_transpose_w(
    const float* __restrict__ cw, float* __restrict__ wTf) {
  int idx = blockIdx.x * 256 + threadIdx.x;  // 786432
  int o = idx & 511;
  int d = (idx >> 9) & 511;
  int t = idx >> 18;
  wTf[idx] = cw[o * 1536 + d * 3 + t];
}

// ---------------------------------------------------------------------------
// K1a: per-row LayerNorm stats. Grid 1024 x 256 thr; wave handles 8 rows.
// ---------------------------------------------------------------------------
__global__ __launch_bounds__(256) void k_stats(const float* __restrict__ x,
                                               float2* __restrict__ stats) {
  int wave = threadIdx.x >> 6, lane = threadIdx.x & 63;
  int row0 = blockIdx.x * 32 + wave * 8;
  for (int j = 0; j < 8; ++j) {
    int row = row0 + j;
    const float4* px = (const float4*)(x + ((size_t)row << 9));
    float4 v0 = px[lane * 2];
    float4 v1 = px[lane * 2 + 1];
    float ps = v0.x + v0.y + v0.z + v0.w + v1.x + v1.y + v1.z + v1.w;
    float pq = v0.x * v0.x + v0.y * v0.y + v0.z * v0.z + v0.w * v0.w +
               v1.x * v1.x + v1.y * v1.y + v1.z * v1.z + v1.w * v1.w;
#pragma unroll
    for (int off = 32; off > 0; off >>= 1) {
      ps += __shfl_down(ps, off);
      pq += __shfl_down(pq, off);
    }
    if (lane == 0) {
      float mu = ps * (1.0f / Dn);
      float var = pq * (1.0f / Dn) - mu * mu;
      stats[row] = make_float2(mu, rsqrtf(var + 1e-5f));
    }
  }
}

// ---------------------------------------------------------------------------
// K1b: radix-4 16-mode DFT projection of LayerNorm output.
// E(s+1024j, k) = E(s,k) * (-i)^{jk}, so rows {s, s+1024, s+2048, s+3072}
// share one twiddle. Chunk c covers base rows c*16..c*16+15 across all 4
// phases (64 rows total). Grid 1024 = b(8) x c(64) x dh(2): d-halved for
// occupancy (16 waves/CU; grid-512 float2 version capped at 8 waves/CU,
// R3 counters: occ 20.8%, both pipes idle). 256 thr, ONE d column each.
// ---------------------------------------------------------------------------
__global__ __launch_bounds__(256) void k_project(
    const float* __restrict__ x, const float* __restrict__ gamma,
    const float* __restrict__ beta, const float2* __restrict__ stats,
    float* __restrict__ partials) {
  int blk = blockIdx.x;
  int b = blk >> 7;
  int c = (blk >> 1) & 63;
  int dh = blk & 1;
  int tid = threadIdx.x;
  int d = (dh << 8) + tid;
  int s_base = c << 4;  // base rows s_base..s_base+15 (0..1023)

  __shared__ __attribute__((aligned(16))) float2 s_tw[16][MODES];  // 2 KB
  __shared__ float2 s_mv[64];                                      // 512 B
  {
    int r = tid >> 4, k = tid & 15;
    int m = ((s_base + r) * k) & (Sn - 1);
    float sn, cn;
    __sincosf((float)m * ANGF, &sn, &cn);
    s_tw[r][k] = make_float2(cn, sn);
    if (tid < 64) {
      // tid = j*16 + r  ->  row = j*1024 + s_base + r
      s_mv[tid] = stats[(b << 12) + ((tid >> 4) << 10) + s_base + (tid & 15)];
    }
  }
  __syncthreads();

  float g = gamma[d], be = beta[d];

  float accRe[MODES], accIm[MODES];
#pragma unroll
  for (int k = 0; k < MODES; k++) { accRe[k] = 0.f; accIm[k] = 0.f; }

  const float* xb = x + (((size_t)b << 12) << 9) + d;
  float cur[4], nxt[4];
#pragma unroll
  for (int j = 0; j < 4; ++j)
    cur[j] = xb[(size_t)((j << 10) + s_base) << 9];

#pragma unroll 2
  for (int r = 0; r < 16; ++r) {
    if (r < 15) {
#pragma unroll
      for (int j = 0; j < 4; ++j)
        nxt[j] = xb[(size_t)((j << 10) + s_base + r + 1) << 9];
    }
    // LayerNorm the 4 phase values
    float xn[4];
#pragma unroll
    for (int j = 0; j < 4; ++j) {
      float2 mv = s_mv[(j << 4) + r];
      xn[j] = (cur[j] - mv.x) * (mv.y * g) + be;
    }
    // radix-4 butterfly (real inputs)
    float t02p = xn[0] + xn[2], t02m = xn[0] - xn[2];
    float t13p = xn[1] + xn[3], t13m = xn[1] - xn[3];
    float u0 = t02p + t13p;  // k%4==0
    float u1 = t02p - t13p;  // k%4==2

    const float4* twr = (const float4*)&s_tw[r][0];
#pragma unroll
    for (int kk = 0; kk < 8; ++kk) {
      float4 t2 = twr[kk];  // (cos,sin) of modes 2kk and 2kk+1
      const int k0 = 2 * kk, k1 = 2 * kk + 1;
      {  // even mode: real combined input
        float u = ((k0 & 3) == 0) ? u0 : u1;
        accRe[k0] += u * t2.x;
        accIm[k0] -= u * t2.y;
      }
      if ((k1 & 3) == 1) {  // F = t02m - i*t13m ; acc += (c - i s)*F
        accRe[k1] += t2.z * t02m - t2.w * t13m;
        accIm[k1] -= t2.z * t13m + t2.w * t02m;
      } else {  // k%4==3: F = t02m + i*t13m
        accRe[k1] += t2.z * t02m + t2.w * t13m;
        accIm[k1] += t2.z * t13m - t2.w * t02m;
      }
    }
#pragma unroll
    for (int j = 0; j < 4; ++j) cur[j] = nxt[j];
  }

  size_t base = ((size_t)(b * 64 + c)) * MODES;
  float2* P2 = (float2*)partials;
#pragma unroll
  for (int k = 0; k < MODES; k++)
    P2[(base + k) * Dn + d] = make_float2(accRe[k], accIm[k]);
}

// ---------------------------------------------------------------------------
// K2: reduce partials over 64 chunks, apply spectral weight, ortho norms.
// ---------------------------------------------------------------------------
__global__ __launch_bounds__(256) void k_reduce_modes(
    const float* __restrict__ partials, const float* __restrict__ wr,
    const float* __restrict__ wi, float* __restrict__ Y) {
  int idx = blockIdx.x * 256 + threadIdx.x;  // 65536
  int d = idx & 511;
  int k = (idx >> 9) & 15;
  int b = idx >> 13;
  const float2* P = (const float2*)partials;
  float re = 0.f, im = 0.f;
#pragma unroll 8
  for (int c = 0; c < 64; c++) {
    float2 p = P[(((size_t)(b * 64 + c)) * MODES + k) * Dn + d];
    re += p.x;
    im += p.y;
  }
  float wrv = wr[d * MODES + k];
  float wiv = wi[d * MODES + k];
  float yre = re * wrv - im * wiv;
  float yim = re * wiv + im * wrv;
  float scale = (k == 0) ? (1.0f / 4096.0f) : (2.0f / 4096.0f);
  ((float2*)Y)[((size_t)b * MODES + k) * Dn + d] =
      make_float2(yre * scale, yim * scale);
}

// ---------------------------------------------------------------------------
// KZ: Zp[dch][b,t][k][o] = sum_{d in chunk} Yhat[b,k,d] * w[o,d,t].
// Grid 768 = b(8) x t(3) x och(8) x dch(4). Wave = 4 modes, lanes = 64 o
// (64-lane-coalesced wTf walk, 256B/wave-step). Depth-1 prefetch on wv.
// ---------------------------------------------------------------------------
__global__ __launch_bounds__(256) void k_build_z(
    const float* __restrict__ Y, const float* __restrict__ wTf,
    float* __restrict__ Zp) {
  int blk = blockIdx.x;
  int b = blk / 96;
  int rem = blk % 96;
  int t = rem >> 5;
  int r2 = rem & 31;
  int och = r2 >> 2;
  int dch = r2 & 3;
  int tid = threadIdx.x;
  int oi = tid & 63, kq = tid >> 6;
  int o = och * 64 + oi;
  int d0 = dch * 128;

  __shared__ float2 Ys[MODES][128];  // 16 KB
  const float2* Y2 = (const float2*)Y;
#pragma unroll
  for (int i = 0; i < 8; i++) {
    int e = tid + i * 256;  // 2048
    int k = e >> 7, dd = e & 127;
    Ys[k][dd] = Y2[(((size_t)(b * MODES + k)) << 9) + d0 + dd];
  }
  __syncthreads();

  float zc[4] = {0.f, 0.f, 0.f, 0.f}, zs[4] = {0.f, 0.f, 0.f, 0.f};
  const float* wp = wTf + (((size_t)(t * Dn + d0)) << 9) + o;
  float wv_n = wp[0];
  for (int dd = 0; dd < 128; ++dd) {
    float wv = wv_n;
    if (dd < 127) wv_n = wp[(size_t)(dd + 1) << 9];
#pragma unroll
    for (int m = 0; m < 4; m++) {
      float2 y = Ys[kq * 4 + m][dd];
      zc[m] += y.x * wv;
      zs[m] += y.y * wv;
    }
  }
  float2* Z2 = (float2*)Zp;
#pragma unroll
  for (int m = 0; m < 4; m++) {
    int k = kq * 4 + m;
    Z2[(((size_t)(dch * 24 + b * 3 + t) * MODES + k)) << 9 | o] =
        make_float2(zc[m], zs[m]);
  }
}

// ---------------------------------------------------------------------------
// KG: G[b][k][o] = Yhat + e^{-i phi} Z0 + Z1 + e^{+i phi} Z2 (phi = 2pi k/S),
// summing the 4 d-chunk partials of Z; conv_b folded into Gc[0] (k=0 twiddle
// == 1 for every s and every phase). Boundary vectors V0 = sum_k
// Re(e^{-i phi} Z0) (s=0 wrap), V1 = sum_k Re(Z2) (s=S-1). Grid 288 x 256.
// ---------------------------------------------------------------------------
__global__ __launch_bounds__(256) void k_build_g(
    const float* __restrict__ Y, const float* __restrict__ Zp,
    const float* __restrict__ conv_b, float* __restrict__ G,
    float* __restrict__ V) {
  int idx = blockIdx.x * 256 + threadIdx.x;
  const float2* Y2 = (const float2*)Y;
  const float2* Z2 = (const float2*)Zp;
  if (idx < 65536) {
    int o = idx & 511;
    int k = (idx >> 9) & 15;
    int b = idx >> 13;
    float2 z0 = make_float2(0.f, 0.f), z1 = z0, z2 = z0;
#pragma unroll
    for (int dch = 0; dch < 4; dch++) {
      float2 a0 = Z2[(((size_t)(dch * 24 + b * 3 + 0) * MODES + k)) << 9 | o];
      float2 a1 = Z2[(((size_t)(dch * 24 + b * 3 + 1) * MODES + k)) << 9 | o];
      float2 a2 = Z2[(((size_t)(dch * 24 + b * 3 + 2) * MODES + k)) << 9 | o];
      z0.x += a0.x; z0.y += a0.y;
      z1.x += a1.x; z1.y += a1.y;
      z2.x += a2.x; z2.y += a2.y;
    }
    float2 y = Y2[(((size_t)(b * MODES + k)) << 9) + o];
    float sf, cf;
    __sincosf((float)k * ANGF, &sf, &cf);
    float gc = y.x + (cf * z0.x + sf * z0.y) + z1.x + (cf * z2.x - sf * z2.y);
    float gs = y.y + (cf * z0.y - sf * z0.x) + z1.y + (cf * z2.y + sf * z2.x);
    if (k == 0) gc += conv_b[o];
    G[(((size_t)(b * MODES + k) * 2 + 0)) << 9 | o] = gc;
    G[(((size_t)(b * MODES + k) * 2 + 1)) << 9 | o] = gs;
  } else if (idx < 65536 + 8192) {
    int j = idx - 65536;
    int o = j & 511;
    int comp = (j >> 9) & 1;
    int b = j >> 10;
    float v = 0.f;
#pragma unroll
    for (int k = 0; k < MODES; k++) {
      float2 z = make_float2(0.f, 0.f);
#pragma unroll
      for (int dch = 0; dch < 4; dch++) {
        float2 a = Z2[(((size_t)(dch * 24 + b * 3 + (comp ? 2 : 0)) * MODES +
                        k)) << 9 | o];
        z.x += a.x; z.y += a.y;
      }
      if (comp == 0) {
        float sf, cf;
        __sincosf((float)k * ANGF, &sf, &cf);
        v += cf * z.x + sf * z.y;
      } else {
        v += z.x;
      }
    }
    V[((size_t)(b * 2 + comp) << 9) + o] = v;
  }
}

// ---------------------------------------------------------------------------
// K5: out[b,s,o] = x + sum_k Re(G_k * e^{i*2pi*s*k/S}) (conv_b folded into
// Gc[0]), minus V0 at s=0 / V1 at s=S-1. Radix-4 over phases j*1024 via
// i^{jk}. Grid 1024 = b(8) x rt(128); 8 base rows per block; float2 of o
// per thread.
// ---------------------------------------------------------------------------
__global__ __launch_bounds__(256) void k_apply(
    const float* __restrict__ x, const float* __restrict__ G,
    const float* __restrict__ V, float* __restrict__ out) {
  int b = blockIdx.x >> 7;
  int rt = blockIdx.x & 127;
  int r0 = rt << 3;  // base rows r0..r0+7 (0..1023)
  int tid = threadIdx.x;
  int o0 = tid << 1;

  __shared__ __attribute__((aligned(16))) float2 s_tw[8][MODES];  // 1 KB
  if (tid < 128) {
    int rr = tid >> 4, k = tid & 15;
    int m = ((r0 + rr) * k) & (Sn - 1);
    float sn, cn;
    __sincosf((float)m * ANGF, &sn, &cn);
    s_tw[rr][k] = make_float2(cn, sn);
  }

  float2 Gc[MODES], Gs[MODES];
  const float2* Gp = (const float2*)(G + ((size_t)b * MODES * 2 * Dn));
#pragma unroll
  for (int k = 0; k < MODES; k++) {
    Gc[k] = Gp[(k * 2 + 0) * 256 + tid];
    Gs[k] = Gp[(k * 2 + 1) * 256 + tid];
  }
  float2 v0 = *(const float2*)&V[((size_t)(b * 2 + 0) << 9) + o0];
  float2 v1 = *(const float2*)&V[((size_t)(b * 2 + 1) << 9) + o0];
  __syncthreads();

  const float* xb = x + (((size_t)b << 12) << 9) + o0;
  float* ob = out + (((size_t)b << 12) << 9) + o0;

  float2 cur[4], nxt[4];
#pragma unroll
  for (int j = 0; j < 4; ++j)
    cur[j] = *(const float2*)(xb + ((size_t)((j << 10) + r0) << 9));

#pragma unroll 2
  for (int rr = 0; rr < 8; ++rr) {
    if (rr < 7) {
#pragma unroll
      for (int j = 0; j < 4; ++j)
        nxt[j] = *(const float2*)(xb + ((size_t)((j << 10) + r0 + rr + 1) << 9));
    }
    float2 a0 = make_float2(0.f, 0.f), a1 = a0, a2 = a0, a3 = a0;
    const float4* twr = (const float4*)&s_tw[rr][0];
#pragma unroll
    for (int kk = 0; kk < 8; ++kk) {
      float4 t2 = twr[kk];
#define APPLY_K(kidx, cc, ss)                                          \
  {                                                                    \
    float2 Pre = make_float2(cc * Gc[kidx].x - ss * Gs[kidx].x,        \
                             cc * Gc[kidx].y - ss * Gs[kidx].y);       \
    float2 Pim = make_float2(cc * Gs[kidx].x + ss * Gc[kidx].x,        \
                             cc * Gs[kidx].y + ss * Gc[kidx].y);       \
    a0.x += Pre.x; a0.y += Pre.y;                                      \
    if (((kidx) & 3) == 0) {                                           \
      a1.x += Pre.x; a1.y += Pre.y;                                    \
      a2.x += Pre.x; a2.y += Pre.y;                                    \
      a3.x += Pre.x; a3.y += Pre.y;                                    \
    } else if (((kidx) & 3) == 1) {                                    \
      a1.x -= Pim.x; a1.y -= Pim.y;                                    \
      a2.x -= Pre.x; a2.y -= Pre.y;                                    \
      a3.x += Pim.x; a3.y += Pim.y;                                    \
    } else if (((kidx) & 3) == 2) {                                    \
      a1.x -= Pre.x; a1.y -= Pre.y;                                    \
      a2.x += Pre.x; a2.y += Pre.y;                                    \
      a3.x -= Pre.x; a3.y -= Pre.y;                                    \
    } else {                                                           \
      a1.x += Pim.x; a1.y += Pim.y;                                    \
      a2.x -= Pre.x; a2.y -= Pre.y;                                    \
      a3.x -= Pim.x; a3.y -= Pim.y;                                    \
    }                                                                  \
  }
      APPLY_K(2 * kk, t2.x, t2.y);
      APPLY_K(2 * kk + 1, t2.z, t2.w);
#undef APPLY_K
    }
    int s_r = r0 + rr;
#pragma unroll
    for (int j = 0; j < 4; ++j) {
      float2 aj = (j == 0) ? a0 : (j == 1) ? a1 : (j == 2) ? a2 : a3;
      int s = s_r + (j << 10);
      float2 o2 = make_float2(cur[j].x + aj.x, cur[j].y + aj.y);
      if (s == 0) { o2.x -= v0.x; o2.y -= v0.y; }
      if (s == Sn - 1) { o2.x -= v1.x; o2.y -= v1.y; }
      *(float2*)(ob + ((size_t)s << 9)) = o2;
    }
#pragma unroll
    for (int j = 0; j < 4; ++j) cur[j] = nxt[j];
  }
}

// ---------------------------------------------------------------------------
extern "C" void kernel_launch(void* const* d_in, const int* in_sizes, int n_in,
                              void* d_out, int out_size, void* d_ws,
                              size_t ws_size, hipStream_t stream) {
  const float* x = (const float*)d_in[0];
  const float* gamma = (const float*)d_in[1];
  const float* beta = (const float*)d_in[2];
  const float* wr = (const float*)d_in[3];
  const float* wi = (const float*)d_in[4];
  const float* conv_w = (const float*)d_in[5];
  const float* conv_b = (const float*)d_in[6];
  float* out = (float*)d_out;

  float* ws = (float*)d_ws;
  float* partials = ws + PART_OFF;
  float* Y = ws + Y_OFF;
  float* wTf = ws + WTF_OFF;
  float* Zp = ws + ZP_OFF;
  float* G = ws + G_OFF;
  float* V = ws + V_OFF;
  float2* stats = (float2*)(ws + STATS_OFF);

  hipLaunchKernelGGL(k_transpose_w, dim3(3072), dim3(256), 0, stream, conv_w,
                     wTf);
  hipLaunchKernelGGL(k_stats, dim3(1024), dim3(256), 0, stream, x, stats);
  hipLaunchKernelGGL(k_project, dim3(1024), dim3(256), 0, stream, x, gamma,
                     beta, stats, partials);
  hipLaunchKernelGGL(k_reduce_modes, dim3(256), dim3(256), 0, stream, partials,
                     wr, wi, Y);
  hipLaunchKernelGGL(k_build_z, dim3(768), dim3(256), 0, stream, Y, wTf, Zp);
  hipLaunchKernelGGL(k_build_g, dim3(288), dim3(256), 0, stream, Y, Zp, conv_b,
                     G, V);
  hipLaunchKernelGGL(k_apply, dim3(1024), dim3(256), 0, stream, x, G, V, out);
}

// Round 9
// 185.364 us; speedup vs baseline: 1.1212x; 1.0205x over previous
//
#include <hip/hip_runtime.h>
#include <hip/hip_bf16.h>
#include <math.h>

// Problem constants
#define Bn 8
#define Sn 4096
#define Dn 512
#define MODES 16
#define ANGF 0.0015339807878856412f  // 2*pi/4096

// ws layout (floats):
#define PART_OFF 0               //  4,194,304  fp32 [B*32][16][512] float2
#define Y_OFF 8388608            //  + 131,072  fp32 [B][16][512] float2
#define WTF_OFF 8519680          //  + 786,432  fp32 [3][512 d][512 o]
#define ZP_OFF 9306112           //  +1,572,864 fp32 [4 dch][B*3][16][512] float2
#define G_OFF 10878976           //  + 131,072  fp32 [B][16][2][512]
#define V_OFF 11010048           //  +   8,192  fp32 [B][2][512]
#define STATS_OFF 11018240       //  +  65,536  fp32 [B*4096] float2 (mu, rstd)

// ---------------------------------------------------------------------------
// K0: transpose conv_w (O,I,3) -> wTf[t][d][o] (coalesced o-writes)
// ---------------------------------------------------------------------------
__global__ __launch_bounds__(256) void k_transpose_w(
    const float* __restrict__ cw, float* __restrict__ wTf) {
  int idx = blockIdx.x * 256 + threadIdx.x;  // 786432
  int o = idx & 511;
  int d = (idx >> 9) & 511;
  int t = idx >> 18;
  wTf[idx] = cw[o * 1536 + d * 3 + t];
}

// ---------------------------------------------------------------------------
// K1a: per-row LayerNorm stats. Grid 1024 x 256 thr; wave handles 8 rows.
// ---------------------------------------------------------------------------
__global__ __launch_bounds__(256) void k_stats(const float* __restrict__ x,
                                               float2* __restrict__ stats) {
  int wave = threadIdx.x >> 6, lane = threadIdx.x & 63;
  int row0 = blockIdx.x * 32 + wave * 8;
  for (int j = 0; j < 8; ++j) {
    int row = row0 + j;
    const float4* px = (const float4*)(x + ((size_t)row << 9));
    float4 v0 = px[lane * 2];
    float4 v1 = px[lane * 2 + 1];
    float ps = v0.x + v0.y + v0.z + v0.w + v1.x + v1.y + v1.z + v1.w;
    float pq = v0.x * v0.x + v0.y * v0.y + v0.z * v0.z + v0.w * v0.w +
               v1.x * v1.x + v1.y * v1.y + v1.z * v1.z + v1.w * v1.w;
#pragma unroll
    for (int off = 32; off > 0; off >>= 1) {
      ps += __shfl_down(ps, off);
      pq += __shfl_down(pq, off);
    }
    if (lane == 0) {
      float mu = ps * (1.0f / Dn);
      float var = pq * (1.0f / Dn) - mu * mu;
      stats[row] = make_float2(mu, rsqrtf(var + 1e-5f));
    }
  }
}

// ---------------------------------------------------------------------------
// K1b: radix-4 16-mode DFT projection of LayerNorm output.
// E(s+1024j, k) = E(s,k) * (-i)^{jk}, so rows {s, s+1024, s+2048, s+3072}
// share one twiddle. Chunk-group cg covers base rows cg*32..cg*32+31 across
// all 4 phases (128 rows): 2 old chunks per block, accumulators held in
// registers -> partials traffic HALVED (33.5 -> 16.8 MB each way).
// Grid 512 = b(8) x cg(32) x dh(2); 256 thr, ONE d column each.
// ---------------------------------------------------------------------------
__global__ __launch_bounds__(256) void k_project(
    const float* __restrict__ x, const float* __restrict__ gamma,
    const float* __restrict__ beta, const float2* __restrict__ stats,
    float* __restrict__ partials) {
  int blk = blockIdx.x;
  int b = blk >> 6;
  int cg = (blk >> 1) & 31;
  int dh = blk & 1;
  int tid = threadIdx.x;
  int d = (dh << 8) + tid;
  int s_base = cg << 5;  // base rows s_base..s_base+31 (0..1023)

  __shared__ __attribute__((aligned(16))) float2 s_tw[32][MODES];  // 4 KB
  __shared__ float2 s_mv[128];                                     // 1 KB
#pragma unroll
  for (int u = 0; u < 2; ++u) {
    int e = (u << 8) + tid;  // 0..511
    int r = e >> 4, k = e & 15;
    int m = ((s_base + r) * k) & (Sn - 1);
    float sn, cn;
    __sincosf((float)m * ANGF, &sn, &cn);
    s_tw[r][k] = make_float2(cn, sn);
  }
  if (tid < 128) {
    // tid = j*32 + r  ->  row = j*1024 + s_base + r
    s_mv[tid] = stats[(b << 12) + ((tid >> 5) << 10) + s_base + (tid & 31)];
  }
  __syncthreads();

  float g = gamma[d], be = beta[d];

  float accRe[MODES], accIm[MODES];
#pragma unroll
  for (int k = 0; k < MODES; k++) { accRe[k] = 0.f; accIm[k] = 0.f; }

  const float* xb = x + (((size_t)b << 12) << 9) + d;
  float cur[4], nxt[4];
#pragma unroll
  for (int j = 0; j < 4; ++j)
    cur[j] = xb[(size_t)((j << 10) + s_base) << 9];

#pragma unroll 2
  for (int r = 0; r < 32; ++r) {
    if (r < 31) {
#pragma unroll
      for (int j = 0; j < 4; ++j)
        nxt[j] = xb[(size_t)((j << 10) + s_base + r + 1) << 9];
    }
    // LayerNorm the 4 phase values
    float xn[4];
#pragma unroll
    for (int j = 0; j < 4; ++j) {
      float2 mv = s_mv[(j << 5) + r];
      xn[j] = (cur[j] - mv.x) * (mv.y * g) + be;
    }
    // radix-4 butterfly (real inputs)
    float t02p = xn[0] + xn[2], t02m = xn[0] - xn[2];
    float t13p = xn[1] + xn[3], t13m = xn[1] - xn[3];
    float u0 = t02p + t13p;  // k%4==0
    float u1 = t02p - t13p;  // k%4==2

    const float4* twr = (const float4*)&s_tw[r][0];
#pragma unroll
    for (int kk = 0; kk < 8; ++kk) {
      float4 t2 = twr[kk];  // (cos,sin) of modes 2kk and 2kk+1
      const int k0 = 2 * kk, k1 = 2 * kk + 1;
      {  // even mode: real combined input
        float u = ((k0 & 3) == 0) ? u0 : u1;
        accRe[k0] += u * t2.x;
        accIm[k0] -= u * t2.y;
      }
      if ((k1 & 3) == 1) {  // F = t02m - i*t13m ; acc += (c - i s)*F
        accRe[k1] += t2.z * t02m - t2.w * t13m;
        accIm[k1] -= t2.z * t13m + t2.w * t02m;
      } else {  // k%4==3: F = t02m + i*t13m
        accRe[k1] += t2.z * t02m + t2.w * t13m;
        accIm[k1] += t2.z * t13m - t2.w * t02m;
      }
    }
#pragma unroll
    for (int j = 0; j < 4; ++j) cur[j] = nxt[j];
  }

  size_t base = ((size_t)(b * 32 + cg)) * MODES;
  float2* P2 = (float2*)partials;
#pragma unroll
  for (int k = 0; k < MODES; k++)
    P2[(base + k) * Dn + d] = make_float2(accRe[k], accIm[k]);
}

// ---------------------------------------------------------------------------
// K2: reduce partials over 32 chunk-groups, apply spectral weight, norms.
// ---------------------------------------------------------------------------
__global__ __launch_bounds__(256) void k_reduce_modes(
    const float* __restrict__ partials, const float* __restrict__ wr,
    const float* __restrict__ wi, float* __restrict__ Y) {
  int idx = blockIdx.x * 256 + threadIdx.x;  // 65536
  int d = idx & 511;
  int k = (idx >> 9) & 15;
  int b = idx >> 13;
  const float2* P = (const float2*)partials;
  float re = 0.f, im = 0.f;
#pragma unroll 8
  for (int c = 0; c < 32; c++) {
    float2 p = P[(((size_t)(b * 32 + c)) * MODES + k) * Dn + d];
    re += p.x;
    im += p.y;
  }
  float wrv = wr[d * MODES + k];
  float wiv = wi[d * MODES + k];
  float yre = re * wrv - im * wiv;
  float yim = re * wiv + im * wrv;
  float scale = (k == 0) ? (1.0f / 4096.0f) : (2.0f / 4096.0f);
  ((float2*)Y)[((size_t)b * MODES + k) * Dn + d] =
      make_float2(yre * scale, yim * scale);
}

// ---------------------------------------------------------------------------
// KZ: Zp[dch][b,t][k][o] = sum_{d in chunk} Yhat[b,k,d] * w[o,d,t].
// Grid 768 = b(8) x t(3) x och(8) x dch(4). Wave = 4 modes, lanes = 64 o
// (64-lane-coalesced wTf walk, 256B/wave-step). Depth-1 prefetch on wv.
// ---------------------------------------------------------------------------
__global__ __launch_bounds__(256) void k_build_z(
    const float* __restrict__ Y, const float* __restrict__ wTf,
    float* __restrict__ Zp) {
  int blk = blockIdx.x;
  int b = blk / 96;
  int rem = blk % 96;
  int t = rem >> 5;
  int r2 = rem & 31;
  int och = r2 >> 2;
  int dch = r2 & 3;
  int tid = threadIdx.x;
  int oi = tid & 63, kq = tid >> 6;
  int o = och * 64 + oi;
  int d0 = dch * 128;

  __shared__ float2 Ys[MODES][128];  // 16 KB
  const float2* Y2 = (const float2*)Y;
#pragma unroll
  for (int i = 0; i < 8; i++) {
    int e = tid + i * 256;  // 2048
    int k = e >> 7, dd = e & 127;
    Ys[k][dd] = Y2[(((size_t)(b * MODES + k)) << 9) + d0 + dd];
  }
  __syncthreads();

  float zc[4] = {0.f, 0.f, 0.f, 0.f}, zs[4] = {0.f, 0.f, 0.f, 0.f};
  const float* wp = wTf + (((size_t)(t * Dn + d0)) << 9) + o;
  float wv_n = wp[0];
  for (int dd = 0; dd < 128; ++dd) {
    float wv = wv_n;
    if (dd < 127) wv_n = wp[(size_t)(dd + 1) << 9];
#pragma unroll
    for (int m = 0; m < 4; m++) {
      float2 y = Ys[kq * 4 + m][dd];
      zc[m] += y.x * wv;
      zs[m] += y.y * wv;
    }
  }
  float2* Z2 = (float2*)Zp;
#pragma unroll
  for (int m = 0; m < 4; m++) {
    int k = kq * 4 + m;
    Z2[(((size_t)(dch * 24 + b * 3 + t) * MODES + k)) << 9 | o] =
        make_float2(zc[m], zs[m]);
  }
}

// ---------------------------------------------------------------------------
// KG: G[b][k][o] = Yhat + e^{-i phi} Z0 + Z1 + e^{+i phi} Z2 (phi = 2pi k/S),
// summing the 4 d-chunk partials of Z; conv_b folded into Gc[0] (k=0 twiddle
// == 1 for every s and every phase). Boundary vectors V0 = sum_k
// Re(e^{-i phi} Z0) (s=0 wrap), V1 = sum_k Re(Z2) (s=S-1). Grid 288 x 256.
// ---------------------------------------------------------------------------
__global__ __launch_bounds__(256) void k_build_g(
    const float* __restrict__ Y, const float* __restrict__ Zp,
    const float* __restrict__ conv_b, float* __restrict__ G,
    float* __restrict__ V) {
  int idx = blockIdx.x * 256 + threadIdx.x;
  const float2* Y2 = (const float2*)Y;
  const float2* Z2 = (const float2*)Zp;
  if (idx < 65536) {
    int o = idx & 511;
    int k = (idx >> 9) & 15;
    int b = idx >> 13;
    float2 z0 = make_float2(0.f, 0.f), z1 = z0, z2 = z0;
#pragma unroll
    for (int dch = 0; dch < 4; dch++) {
      float2 a0 = Z2[(((size_t)(dch * 24 + b * 3 + 0) * MODES + k)) << 9 | o];
      float2 a1 = Z2[(((size_t)(dch * 24 + b * 3 + 1) * MODES + k)) << 9 | o];
      float2 a2 = Z2[(((size_t)(dch * 24 + b * 3 + 2) * MODES + k)) << 9 | o];
      z0.x += a0.x; z0.y += a0.y;
      z1.x += a1.x; z1.y += a1.y;
      z2.x += a2.x; z2.y += a2.y;
    }
    float2 y = Y2[(((size_t)(b * MODES + k)) << 9) + o];
    float sf, cf;
    __sincosf((float)k * ANGF, &sf, &cf);
    float gc = y.x + (cf * z0.x + sf * z0.y) + z1.x + (cf * z2.x - sf * z2.y);
    float gs = y.y + (cf * z0.y - sf * z0.x) + z1.y + (cf * z2.y + sf * z2.x);
    if (k == 0) gc += conv_b[o];
    G[(((size_t)(b * MODES + k) * 2 + 0)) << 9 | o] = gc;
    G[(((size_t)(b * MODES + k) * 2 + 1)) << 9 | o] = gs;
  } else if (idx < 65536 + 8192) {
    int j = idx - 65536;
    int o = j & 511;
    int comp = (j >> 9) & 1;
    int b = j >> 10;
    float v = 0.f;
#pragma unroll
    for (int k = 0; k < MODES; k++) {
      float2 z = make_float2(0.f, 0.f);
#pragma unroll
      for (int dch = 0; dch < 4; dch++) {
        float2 a = Z2[(((size_t)(dch * 24 + b * 3 + (comp ? 2 : 0)) * MODES +
                        k)) << 9 | o];
        z.x += a.x; z.y += a.y;
      }
      if (comp == 0) {
        float sf, cf;
        __sincosf((float)k * ANGF, &sf, &cf);
        v += cf * z.x + sf * z.y;
      } else {
        v += z.x;
      }
    }
    V[((size_t)(b * 2 + comp) << 9) + o] = v;
  }
}

// ---------------------------------------------------------------------------
// K5: out[b,s,o] = x + sum_k Re(G_k * e^{i*2pi*s*k/S}) (conv_b folded into
// Gc[0]), minus V0 at s=0 / V1 at s=S-1. Radix-4 over phases j*1024 via
// i^{jk}. Grid 1024 = b(8) x rt(128); 8 base rows per block; float2 of o
// per thread.
// ---------------------------------------------------------------------------
__global__ __launch_bounds__(256) void k_apply(
    const float* __restrict__ x, const float* __restrict__ G,
    const float* __restrict__ V, float* __restrict__ out) {
  int b = blockIdx.x >> 7;
  int rt = blockIdx.x & 127;
  int r0 = rt << 3;  // base rows r0..r0+7 (0..1023)
  int tid = threadIdx.x;
  int o0 = tid << 1;

  __shared__ __attribute__((aligned(16))) float2 s_tw[8][MODES];  // 1 KB
  if (tid < 128) {
    int rr = tid >> 4, k = tid & 15;
    int m = ((r0 + rr) * k) & (Sn - 1);
    float sn, cn;
    __sincosf((float)m * ANGF, &sn, &cn);
    s_tw[rr][k] = make_float2(cn, sn);
  }

  float2 Gc[MODES], Gs[MODES];
  const float2* Gp = (const float2*)(G + ((size_t)b * MODES * 2 * Dn));
#pragma unroll
  for (int k = 0; k < MODES; k++) {
    Gc[k] = Gp[(k * 2 + 0) * 256 + tid];
    Gs[k] = Gp[(k * 2 + 1) * 256 + tid];
  }
  float2 v0 = *(const float2*)&V[((size_t)(b * 2 + 0) << 9) + o0];
  float2 v1 = *(const float2*)&V[((size_t)(b * 2 + 1) << 9) + o0];
  __syncthreads();

  const float* xb = x + (((size_t)b << 12) << 9) + o0;
  float* ob = out + (((size_t)b << 12) << 9) + o0;

  float2 cur[4], nxt[4];
#pragma unroll
  for (int j = 0; j < 4; ++j)
    cur[j] = *(const float2*)(xb + ((size_t)((j << 10) + r0) << 9));

#pragma unroll 2
  for (int rr = 0; rr < 8; ++rr) {
    if (rr < 7) {
#pragma unroll
      for (int j = 0; j < 4; ++j)
        nxt[j] = *(const float2*)(xb + ((size_t)((j << 10) + r0 + rr + 1) << 9));
    }
    float2 a0 = make_float2(0.f, 0.f), a1 = a0, a2 = a0, a3 = a0;
    const float4* twr = (const float4*)&s_tw[rr][0];
#pragma unroll
    for (int kk = 0; kk < 8; ++kk) {
      float4 t2 = twr[kk];
#define APPLY_K(kidx, cc, ss)                                          \
  {                                                                    \
    float2 Pre = make_float2(cc * Gc[kidx].x - ss * Gs[kidx].x,        \
                             cc * Gc[kidx].y - ss * Gs[kidx].y);       \
    float2 Pim = make_float2(cc * Gs[kidx].x + ss * Gc[kidx].x,        \
                             cc * Gs[kidx].y + ss * Gc[kidx].y);       \
    a0.x += Pre.x; a0.y += Pre.y;                                      \
    if (((kidx) & 3) == 0) {                                           \
      a1.x += Pre.x; a1.y += Pre.y;                                    \
      a2.x += Pre.x; a2.y += Pre.y;                                    \
      a3.x += Pre.x; a3.y += Pre.y;                                    \
    } else if (((kidx) & 3) == 1) {                                    \
      a1.x -= Pim.x; a1.y -= Pim.y;                                    \
      a2.x -= Pre.x; a2.y -= Pre.y;                                    \
      a3.x += Pim.x; a3.y += Pim.y;                                    \
    } else if (((kidx) & 3) == 2) {                                    \
      a1.x -= Pre.x; a1.y -= Pre.y;                                    \
      a2.x += Pre.x; a2.y += Pre.y;                                    \
      a3.x -= Pre.x; a3.y -= Pre.y;                                    \
    } else {                                                           \
      a1.x += Pim.x; a1.y += Pim.y;                                    \
      a2.x -= Pre.x; a2.y -= Pre.y;                                    \
      a3.x -= Pim.x; a3.y -= Pim.y;                                    \
    }                                                                  \
  }
      APPLY_K(2 * kk, t2.x, t2.y);
      APPLY_K(2 * kk + 1, t2.z, t2.w);
#undef APPLY_K
    }
    int s_r = r0 + rr;
#pragma unroll
    for (int j = 0; j < 4; ++j) {
      float2 aj = (j == 0) ? a0 : (j == 1) ? a1 : (j == 2) ? a2 : a3;
      int s = s_r + (j << 10);
      float2 o2 = make_float2(cur[j].x + aj.x, cur[j].y + aj.y);
      if (s == 0) { o2.x -= v0.x; o2.y -= v0.y; }
      if (s == Sn - 1) { o2.x -= v1.x; o2.y -= v1.y; }
      *(float2*)(ob + ((size_t)s << 9)) = o2;
    }
#pragma unroll
    for (int j = 0; j < 4; ++j) cur[j] = nxt[j];
  }
}

// ---------------------------------------------------------------------------
extern "C" void kernel_launch(void* const* d_in, const int* in_sizes, int n_in,
                              void* d_out, int out_size, void* d_ws,
                              size_t ws_size, hipStream_t stream) {
  const float* x = (const float*)d_in[0];
  const float* gamma = (const float*)d_in[1];
  const float* beta = (const float*)d_in[2];
  const float* wr = (const float*)d_in[3];
  const float* wi = (const float*)d_in[4];
  const float* conv_w = (const float*)d_in[5];
  const float* conv_b = (const float*)d_in[6];
  float* out = (float*)d_out;

  float* ws = (float*)d_ws;
  float* partials = ws + PART_OFF;
  float* Y = ws + Y_OFF;
  float* wTf = ws + WTF_OFF;
  float* Zp = ws + ZP_OFF;
  float* G = ws + G_OFF;
  float* V = ws + V_OFF;
  float2* stats = (float2*)(ws + STATS_OFF);

  hipLaunchKernelGGL(k_transpose_w, dim3(3072), dim3(256), 0, stream, conv_w,
                     wTf);
  hipLaunchKernelGGL(k_stats, dim3(1024), dim3(256), 0, stream, x, stats);
  hipLaunchKernelGGL(k_project, dim3(512), dim3(256), 0, stream, x, gamma,
                     beta, stats, partials);
  hipLaunchKernelGGL(k_reduce_modes, dim3(256), dim3(256), 0, stream, partials,
                     wr, wi, Y);
  hipLaunchKernelGGL(k_build_z, dim3(768), dim3(256), 0, stream, Y, wTf, Zp);
  hipLaunchKernelGGL(k_build_g, dim3(288), dim3(256), 0, stream, Y, Zp, conv_b,
                     G, V);
  hipLaunchKernelGGL(k_apply, dim3(1024), dim3(256), 0, stream, x, G, V, out);
}